// Round 11
// baseline (197.110 us; speedup 1.0000x reference)
//
#include <hip/hip_runtime.h>
#include <hip/hip_bf16.h>
#include <cmath>

#define N_NODES 50000
#define N_EDGES 800000
#define D_IN 256
#define D_HID 128
#define D_ENC 64
#define NBUK 512         // dest buckets, bucket = d >> 7 (391 used)
#define BSH 7
#define BMSK 127
#define BCAP 4096        // bucket capacity (expected ~2046, 2x margin)
#define PBF_EPT 8        // edges per thread in part path (4096/block @ 512 thr)
#define NPARTB 196       // ceil(N_EDGES/4096)
#define NGEMB 782        // ceil(50048/64) GEMM tile-blocks
#define NBUKU 391        // used buckets = ceil(N_NODES/128)
#define NCZB  782        // 2 blocks per used bucket (parity node-split)
#define DYN_LDS 36864

typedef short short8 __attribute__((ext_vector_type(8)));
typedef float floatx4 __attribute__((ext_vector_type(4)));
typedef float floatx8 __attribute__((ext_vector_type(8)));
typedef unsigned short ushort8v __attribute__((ext_vector_type(8)));

static __device__ __forceinline__ unsigned short f2bf(float f) {
    unsigned int u = __float_as_uint(f);
    unsigned int r = (u + 0x7FFFu + ((u >> 16) & 1u)) >> 16;   // RNE
    return (unsigned short)r;
}
static __device__ __forceinline__ float bf2f(unsigned short u) {
    return __uint_as_float(((unsigned int)u) << 16);
}
static __device__ __forceinline__ floatx8 bf2f8(ushort8v u) {
    floatx8 f;
#pragma unroll
    for (int j = 0; j < 8; ++j) f[j] = bf2f(u[j]);
    return f;
}

// ---------------- W pre-swizzle into B-fragment layout (bf16) ----------------
static __device__ __forceinline__ void wswz(const float* __restrict__ W,
                                            unsigned short* __restrict__ Wsw,
                                            int t, int K, int N) {
    int KS = K / 32;
    int lane = t & 63;
    int ks   = (t >> 6) % KS;
    int ct   = (t >> 6) / KS;
    int m = lane & 15, quad = lane >> 4;
    int kbase = ks * 32 + quad * 8;
    int col   = ct * 16 + m;
#pragma unroll
    for (int j = 0; j < 8; ++j)
        Wsw[t * 8 + j] = f2bf(W[(size_t)(kbase + j) * N + col]);
}

// ---------------- k0: weight prep + bcur/rowcnt zero ----------------
__global__ __launch_bounds__(256) void prep_k(const float* __restrict__ W1,
                                              const float* __restrict__ W2,
                                              const float* __restrict__ b2,
                                              const float* __restrict__ Wfc,
                                              unsigned short* __restrict__ Wsw1,
                                              float* __restrict__ w2fc,
                                              float* __restrict__ b2fc,
                                              int* __restrict__ bcur,
                                              int* __restrict__ rowcnt) {
    int gid = blockIdx.x * 256 + threadIdx.x;     // grid 64*256 = 16384
    if (gid < 4096) wswz(W1, Wsw1, gid, D_IN, D_HID);
    else if (gid < 4224) {                        // w2fc[c] = sum_j W2[c][j]*Wfc[j]
        int c = gid - 4096;
        float s = 0.0f;
#pragma unroll 8
        for (int j = 0; j < D_ENC; ++j) s += W2[c * D_ENC + j] * Wfc[j];
        w2fc[c] = s;
    } else if (gid == 4224) {                     // b2fc = b2 @ Wfc
        float s = 0.0f;
        for (int j = 0; j < D_ENC; ++j) s += b2[j] * Wfc[j];
        b2fc[0] = s;
    }
    if (gid < NBUK) bcur[gid] = 0;
    for (int i = gid; i < 50048; i += 16384) rowcnt[i] = 0;
}

// ---------------- device: radix partition of one 4096-edge chunk (512 thr) ----------------
// Also accumulates global per-node in-degree (fire-and-forget atomics, hidden
// under the co-dispatched GEMM).
static __device__ void part_path(char* dynsm, int bid,
                                 const int* rows, const int* cols,
                                 int* bcur, unsigned int* brecs, int* rowcnt) {
    unsigned int* recs = (unsigned int*)dynsm;        // 4096 u32 (16 KB)
    int* h     = (int*)(dynsm + 16384);               // NBUK
    int* ex    = h + NBUK;                            // NBUK
    int* gbase = ex + NBUK;                           // NBUK  (total 22.5 KB)
    int tid = threadIdx.x;
    if (tid < NBUK) h[tid] = 0;
    __syncthreads();
    int e0 = bid * 4096;
    unsigned int myrec[PBF_EPT];
    int myb[PBF_EPT];
#pragma unroll
    for (int j = 0; j < PBF_EPT; ++j) {
        int e = e0 + j * 512 + tid;
        if (e < N_EDGES) {
            int s = __builtin_nontemporal_load(&rows[e]);   // single-touch stream
            int d = __builtin_nontemporal_load(&cols[e]);
            myrec[j] = ((unsigned int)s << 16) | (unsigned int)d;
            myb[j] = d >> BSH;
            atomicAdd(&h[myb[j]], 1);
            atomicAdd(&rowcnt[d], 1);                 // global in-degree
        } else myb[j] = -1;
    }
    __syncthreads();
    if (tid < NBUK) {
        int c = h[tid];
        gbase[tid] = tid * BCAP + (c ? atomicAdd(&bcur[tid], c) : 0);
        ex[tid] = c;
    }
    __syncthreads();
    for (int off = 1; off < NBUK; off <<= 1) {
        int v = 0;
        if (tid < NBUK && tid >= off) v = ex[tid - off];
        __syncthreads();
        if (tid < NBUK) ex[tid] += v;
        __syncthreads();
    }
    if (tid < NBUK) { ex[tid] -= h[tid]; h[tid] = 0; }
    __syncthreads();
#pragma unroll
    for (int j = 0; j < PBF_EPT; ++j) {
        if (myb[j] >= 0) {
            int p = ex[myb[j]] + atomicAdd(&h[myb[j]], 1);
            recs[p] = myrec[j];
        }
    }
    __syncthreads();
    int w = tid >> 6, lane = tid & 63;
    for (int b = w; b < NBUK; b += 8) {
        int start = ex[b], cnt = h[b], gb = gbase[b];
        int lim = (b + 1) * BCAP;
        for (int i = lane; i < cnt; i += 64) {
            int gp = gb + i;
            if (gp < lim) brecs[gp] = recs[start + i];
        }
    }
}

// ---------------- device: one 64-row MFMA GEMM tile (512 thr) ----------------
// H[r,:] = bf16(X[r,:] @ W1)  (dinv weighting deferred to the gather)
static __device__ void gemm_path(char* dynsm, int row0,
                                 const floatx4* X4, const unsigned short* Wsw,
                                 unsigned short* H) {
    constexpr int KP = D_IN + 8;   // 264
    unsigned short* As = (unsigned short*)dynsm;    // 64*KP u16 (33 KB)
    int tid = threadIdx.x;
    for (int idx = tid; idx < 64 * 64; idx += 512) {
        int r = idx >> 6, c4 = idx & 63;
        int gr = row0 + r;
        floatx4 v = (gr < N_NODES) ? __builtin_nontemporal_load(&X4[(size_t)gr * 64 + c4])
                                   : (floatx4){0, 0, 0, 0};   // X is single-touch
        __hip_bfloat162 p0 = __float22bfloat162_rn(float2{v[0], v[1]});   // packed RNE cvt
        __hip_bfloat162 p1 = __float22bfloat162_rn(float2{v[2], v[3]});
        uint2 u; u.x = *(unsigned int*)&p0; u.y = *(unsigned int*)&p1;
        *(uint2*)&As[r * KP + c4 * 4] = u;
    }
    __syncthreads();

    int w    = tid >> 6;
    int lane = tid & 63;
    int m    = lane & 15;
    int quad = lane >> 4;
    int rsub = w & 3;
    int cth  = w >> 2;              // 0/1: which 4 col-tiles

    floatx4 acc[4];
#pragma unroll
    for (int ct = 0; ct < 4; ++ct)
#pragma unroll
        for (int i = 0; i < 4; ++i) acc[ct][i] = 0.0f;

#pragma unroll
    for (int ks = 0; ks < D_IN / 32; ++ks) {
        short8 af = *(const short8*)&As[(rsub * 16 + m) * KP + ks * 32 + quad * 8];
#pragma unroll
        for (int ct = 0; ct < 4; ++ct) {
            int ct4 = cth * 4 + ct;
            short8 bf = *(const short8*)&Wsw[(size_t)((ct4 * (D_IN / 32) + ks) * 64 + lane) * 8];
            acc[ct] = __builtin_amdgcn_mfma_f32_16x16x32_bf16(af, bf, acc[ct], 0, 0, 0);
        }
    }

    int rbase = row0 + rsub * 16 + quad * 4;
#pragma unroll
    for (int ct = 0; ct < 4; ++ct) {
        int col = (cth * 4 + ct) * 16 + m;
#pragma unroll
        for (int reg = 0; reg < 4; ++reg) {
            int r = rbase + reg;
            if (r < N_NODES) H[(size_t)r * D_HID + col] = f2bf(acc[ct][reg]);
        }
    }
}

// ---------------- D2: part (196) || layer-1 GEMM (782), one dispatch ----------------
__global__ __launch_bounds__(512) void pg_k(const int* __restrict__ rows,
                                            const int* __restrict__ cols,
                                            int* __restrict__ bcur,
                                            unsigned int* __restrict__ brecs,
                                            int* __restrict__ rowcnt,
                                            const floatx4* __restrict__ X4,
                                            const unsigned short* __restrict__ Wsw,
                                            unsigned short* __restrict__ H) {
    extern __shared__ char dynsm[];
    if (blockIdx.x < NPARTB)
        part_path(dynsm, blockIdx.x, rows, cols, bcur, brecs, rowcnt);
    else
        gemm_path(dynsm, (blockIdx.x - NPARTB) * 64, X4, Wsw, H);
}

// x8-deep WEIGHTED gather from LDS-sorted index list:
// acc += rsqrt(rowcnt[s]+1) * h1raw[s]; 8 loads in flight.
#define WGATHER_RC(SP)                                                         \
    {                                                                          \
        const unsigned short* sp_ = (SP);                                      \
        int i = 0;                                                             \
        for (; i + 8 <= cnt; i += 8) {                                         \
            int s0 = sp_[i],     s1 = sp_[i + 1], s2 = sp_[i + 2], s3 = sp_[i + 3]; \
            int s4 = sp_[i + 4], s5 = sp_[i + 5], s6 = sp_[i + 6], s7 = sp_[i + 7]; \
            int c0 = rcg[s0], c1 = rcg[s1], c2 = rcg[s2], c3 = rcg[s3];        \
            int c4 = rcg[s4], c5 = rcg[s5], c6 = rcg[s6], c7 = rcg[s7];        \
            ushort8v v0 = hs[(size_t)s0 * 16 + d8], v1 = hs[(size_t)s1 * 16 + d8]; \
            ushort8v v2 = hs[(size_t)s2 * 16 + d8], v3 = hs[(size_t)s3 * 16 + d8]; \
            ushort8v v4 = hs[(size_t)s4 * 16 + d8], v5 = hs[(size_t)s5 * 16 + d8]; \
            ushort8v v6 = hs[(size_t)s6 * 16 + d8], v7 = hs[(size_t)s7 * 16 + d8]; \
            a0 += bf2f8(v0) * rsqrtf((float)(c0 + 1));                         \
            a1 += bf2f8(v1) * rsqrtf((float)(c1 + 1));                         \
            a2 += bf2f8(v2) * rsqrtf((float)(c2 + 1));                         \
            a3 += bf2f8(v3) * rsqrtf((float)(c3 + 1));                         \
            a0 += bf2f8(v4) * rsqrtf((float)(c4 + 1));                         \
            a1 += bf2f8(v5) * rsqrtf((float)(c5 + 1));                         \
            a2 += bf2f8(v6) * rsqrtf((float)(c6 + 1));                         \
            a3 += bf2f8(v7) * rsqrtf((float)(c7 + 1));                         \
        }                                                                      \
        if (i + 4 <= cnt) {                                                    \
            int s0 = sp_[i], s1 = sp_[i + 1], s2 = sp_[i + 2], s3 = sp_[i + 3]; \
            a0 += bf2f8(hs[(size_t)s0 * 16 + d8]) * rsqrtf((float)(rcg[s0] + 1)); \
            a1 += bf2f8(hs[(size_t)s1 * 16 + d8]) * rsqrtf((float)(rcg[s1] + 1)); \
            a2 += bf2f8(hs[(size_t)s2 * 16 + d8]) * rsqrtf((float)(rcg[s2] + 1)); \
            a3 += bf2f8(hs[(size_t)s3 * 16 + d8]) * rsqrtf((float)(rcg[s3] + 1)); \
            i += 4;                                                            \
        }                                                                      \
        for (; i < cnt; ++i) {                                                 \
            int s = sp_[i];                                                    \
            a0 += bf2f8(hs[(size_t)s * 16 + d8]) * rsqrtf((float)(rcg[s] + 1)); \
        }                                                                      \
    }

// ---------------- D3: fused bucket-sort + gather1 + relu + FC-folded projection ----------------
// 2 blocks per 128-node bucket (parity node-split). Each block counting-sorts its
// bucket's records in LDS (indices stay in LDS -> no srcs round-trip for the gather),
// then computes z[v] = dinv[v]*( relu(dinv[v]*Σ rsqrt(deg_s+1)*h1raw[s] + b1) @ w2fc )
// for its 64 nodes (16 lanes/node, 2 rounds). Parity-0 also writes rowptr/dinv and
// flushes the sorted srcs for the final scalar propagation.
__global__ __launch_bounds__(512) void cz_k(const unsigned int* __restrict__ brecs,
                                            const int* __restrict__ bcur,
                                            int* __restrict__ rowptr,
                                            const int* __restrict__ rowcnt,
                                            float* __restrict__ dinv,
                                            unsigned short* __restrict__ srcs,
                                            const ushort8v* __restrict__ hs,
                                            const float4* __restrict__ b1_4,
                                            const float4* __restrict__ w2fc4,
                                            float* __restrict__ z) {
    __shared__ int ex[128], cur[128], rc[128];
    __shared__ unsigned short sl[BCAP];            // 8 KB sorted source list
    const int* rcg = rowcnt;
    int tid = threadIdx.x;
    int b = blockIdx.x >> 1, par = blockIdx.x & 1;
    int cb = bcur[b]; if (cb > BCAP) cb = BCAP;
    int ebeg = b * BCAP;
    if (tid < 128) ex[tid] = 0;
    __syncthreads();
    for (int e = tid; e < cb; e += 512)
        atomicAdd(&ex[brecs[ebeg + e] & BMSK], 1);
    __syncthreads();
    int v = (tid < 128) ? ex[tid] : 0;
    for (int off = 1; off < 128; off <<= 1) {
        int t = (tid < 128 && tid >= off) ? ex[tid - off] : 0;
        __syncthreads();
        if (tid < 128) ex[tid] += t;
        __syncthreads();
    }
    if (tid < 128) {
        int excl = ex[tid] - v;
        cur[tid] = excl;
        rc[tid]  = v;
        ex[tid]  = excl;
        int node = (b << BSH) + tid;
        if (par == 0 && node < N_NODES) {
            rowptr[node] = ebeg + excl;
            dinv[node]   = rsqrtf((float)(v + 1));   // +1 self-loop
        }
    }
    __syncthreads();
    for (int e = tid; e < cb; e += 512) {
        unsigned int rec = brecs[ebeg + e];
        int p = atomicAdd(&cur[rec & BMSK], 1);
        sl[p] = (unsigned short)(rec >> 16);
    }
    __syncthreads();
    if (par == 0) {                                  // flush for gatherz (coalesced u32)
        int nw = (cb + 1) >> 1;
        unsigned int* s32 = (unsigned int*)(srcs + ebeg);
        const unsigned int* l32 = (const unsigned int*)sl;
        for (int t = tid; t < nw; t += 512) s32[t] = l32[t];
    }

    // gather + projection for this block's 64 nodes
    int ln = tid >> 4, d8 = tid & 15;                // 32 node-groups, 2 rounds
#pragma unroll
    for (int r = 0; r < 2; ++r) {
        int l = par * 64 + r * 32 + ln;
        int node = (b << BSH) + l;
        if (node < N_NODES) {
            int beg = ex[l], cnt = rc[l];
            floatx8 a0 = {0,0,0,0,0,0,0,0}, a1 = a0, a2 = a0, a3 = a0;
            WGATHER_RC(sl + beg)
            float di = rsqrtf((float)(cnt + 1));
            floatx8 acc = a0 + a1 + a2 + a3 + bf2f8(hs[(size_t)node * 16 + d8]) * di;
            float4 bA = b1_4[d8 * 2],  bB = b1_4[d8 * 2 + 1];
            float4 wA = w2fc4[d8 * 2], wB = w2fc4[d8 * 2 + 1];
            float s = fmaxf(di * acc[0] + bA.x, 0.0f) * wA.x
                    + fmaxf(di * acc[1] + bA.y, 0.0f) * wA.y
                    + fmaxf(di * acc[2] + bA.z, 0.0f) * wA.z
                    + fmaxf(di * acc[3] + bA.w, 0.0f) * wA.w
                    + fmaxf(di * acc[4] + bB.x, 0.0f) * wB.x
                    + fmaxf(di * acc[5] + bB.y, 0.0f) * wB.y
                    + fmaxf(di * acc[6] + bB.z, 0.0f) * wB.z
                    + fmaxf(di * acc[7] + bB.w, 0.0f) * wB.w;
#pragma unroll
            for (int off = 8; off; off >>= 1) s += __shfl_xor(s, off, 16);
            if (d8 == 0) z[node] = di * s;
        }
    }
}

// ---------------- D4: scalar propagation + sigmoid ----------------
// out[v] = sigmoid( dinv[v] * (Σ z[nbr] + z[v]) + b2fc + bfc ); z is 200 KB L2-resident.
__global__ __launch_bounds__(256) void gatherz_k(const float* __restrict__ z,
                                                 const int* __restrict__ rowptr,
                                                 const int* __restrict__ rowcnt,
                                                 const unsigned short* __restrict__ srcs,
                                                 const float* __restrict__ dinv,
                                                 const float* __restrict__ b2fc,
                                                 const float* __restrict__ bfc,
                                                 float* __restrict__ out) {
    int v = blockIdx.x * 256 + threadIdx.x;
    if (v >= N_NODES) return;
    int beg = rowptr[v], cnt = rowcnt[v];
    float s0 = z[v], s1 = 0.0f, s2 = 0.0f, s3 = 0.0f;
    int i = beg, end = beg + cnt;
    for (; i + 4 <= end; i += 4) {
        s0 += z[srcs[i]];
        s1 += z[srcs[i + 1]];
        s2 += z[srcs[i + 2]];
        s3 += z[srcs[i + 3]];
    }
    for (; i < end; ++i) s0 += z[srcs[i]];
    float p = dinv[v] * (s0 + s1 + s2 + s3) + b2fc[0] + bfc[0];
    out[v] = 1.0f / (1.0f + expf(-p));
}

extern "C" void kernel_launch(void* const* d_in, const int* in_sizes, int n_in,
                              void* d_out, int out_size, void* d_ws, size_t ws_size,
                              hipStream_t stream) {
    const float* x   = (const float*)d_in[0];
    const int*   ei  = (const int*)d_in[1];     // [2, E] int32
    const float* W1  = (const float*)d_in[2];
    const float* b1  = (const float*)d_in[3];
    const float* W2  = (const float*)d_in[4];
    const float* b2  = (const float*)d_in[5];
    const float* Wfc = (const float*)d_in[6];
    const float* bfc = (const float*)d_in[7];
    float* out = (float*)d_out;

    const int* rows = ei;             // sources
    const int* cols = ei + N_EDGES;   // targets

    // workspace layout (16B alignment kept for vector types)
    float* ws     = (float*)d_ws;
    float* dinv   = ws;                                   // 50048 f
    int*   rowptr = (int*)(ws + 50048);                   // 50048
    int*   rowcnt = rowptr + 50048;                       // 50048
    int*   bcur   = rowcnt + 50048;                       // 512
    unsigned int* brecs = (unsigned int*)(bcur + 512);    // NBUK*BCAP u32 (8MB)
    unsigned short* srcs = (unsigned short*)(brecs + (size_t)NBUK * BCAP);  // 4MB u16
    unsigned short* h1 = srcs + (size_t)NBUK * BCAP;               // 6.4M us (12.8MB)
    unsigned short* Wsw1 = h1 + (size_t)N_NODES * D_HID;           // 32768 us
    float* z    = (float*)(Wsw1 + (size_t)D_IN * D_HID);           // 50000 f
    float* w2fc = z + 50000;                                       // 128 f
    float* b2fc = w2fc + 128;                                      // 1 f

    // ---- D1: weight swizzle + FC fold + bcur/rowcnt zero ----
    prep_k<<<64, 256, 0, stream>>>(W1, W2, b2, Wfc, Wsw1, w2fc, b2fc, bcur, rowcnt);

    // ---- D2: radix partition + degree atomics (196) || layer-1 GEMM (782) ----
    pg_k<<<NPARTB + NGEMB, 512, DYN_LDS, stream>>>(rows, cols, bcur, brecs, rowcnt,
                                                   (const floatx4*)x, Wsw1, h1);

    // ---- D3: fused bucket-sort + gather1 + relu + projection -> z ----
    cz_k<<<NCZB, 512, 0, stream>>>(brecs, bcur, rowptr, rowcnt, dinv, srcs,
                                   (const ushort8v*)h1, (const float4*)b1,
                                   (const float4*)w2fc, z);

    // ---- D4: scalar propagation + sigmoid ----
    gatherz_k<<<(N_NODES + 255) / 256, 256, 0, stream>>>(z, rowptr, rowcnt, srcs, dinv,
                                                         b2fc, bfc, out);
}